// Round 2
// baseline (1294.453 us; speedup 1.0000x reference)
//
#include <hip/hip_runtime.h>

// CAGenerator: 64-step neural CA — ONE dispatch/step.
// R17: ROWS=2 per block. grid 128 x 1024 thr (16 waves, 4/SIMD).
//   Each block: batch b, rows y0..y0+1. Build rebuilds S_s for rows
//   y0-1..y0+2 (msT f16, 4-row halo) from U ch0 / A 6-row halos.
//   phase 1: wave w owns m-tile w (32 H-ch) x 64 px: per ks one A-frag,
//            two B-frags (row0/row1), two MFMAs. Weight stream per block
//            unchanged (720 KB) but covers 2 rows -> aggregate halved.
//   phase 2: waves 0-5 (3 m-tiles x 2 rows) upd = W3*H full-K;
//            Uout = SrowL + upd + b3 (unmasked).
// kF (1 launch): dout = U63 ch0 * live63.
// Folded: Wc = W2@W1 (512x720), bc = W2@b1+b2. mask=uniform()<1.0 -> no RNG.

#define NPIX 8192
#define T_ALIVE 0.01f

typedef _Float16 f16;
typedef __attribute__((ext_vector_type(8)))  _Float16 h8_t;
typedef __attribute__((ext_vector_type(4)))  _Float16 h4_t;
typedef __attribute__((ext_vector_type(16))) float    fx16;

// ---------------------------------------------------------------------------
// Prep (unchanged)
// ---------------------------------------------------------------------------
__global__ __launch_bounds__(256) void tr512(
    const float* __restrict__ W2, float* __restrict__ W2T)
{
    __shared__ float t[32][33];
    const int bx = blockIdx.x & 15, by = blockIdx.x >> 4;
    const int x = threadIdx.x & 31, y8 = threadIdx.x >> 5;
#pragma unroll
    for (int r = 0; r < 32; r += 8)
        t[r + y8][x] = W2[(size_t)(by * 32 + r + y8) * 512 + bx * 32 + x];
    __syncthreads();
#pragma unroll
    for (int r = 0; r < 32; r += 8)
        W2T[(size_t)(bx * 32 + r + y8) * 512 + by * 32 + x] = t[x][r + y8];
}

__global__ __launch_bounds__(256) void wc32(
    const float* __restrict__ W2T, const float* __restrict__ W1,
    float* __restrict__ Wc)
{
    __shared__ float As[16][32];
    __shared__ float Bs[16][32];
    const int tid = threadIdx.x;
    const int ty = tid >> 3, tx = tid & 7;
    const int m0 = blockIdx.y * 32, n0 = blockIdx.x * 32;
    float acc[4] = {0.f, 0.f, 0.f, 0.f};

    for (int k0 = 0; k0 < 512; k0 += 16) {
#pragma unroll
        for (int t = 0; t < 2; ++t) {
            const int idx = tid + t * 256;
            const int r = idx >> 5, c = idx & 31;
            As[r][c] = W2T[(size_t)(k0 + r) * 512 + m0 + c];
            const int n = n0 + c;
            Bs[r][c] = (n < 720) ? W1[(size_t)(k0 + r) * 720 + n] : 0.f;
        }
        __syncthreads();
#pragma unroll
        for (int kk = 0; kk < 16; ++kk) {
            const float a = As[kk][ty];
#pragma unroll
            for (int j = 0; j < 4; ++j)
                acc[j] = fmaf(a, Bs[kk][tx * 4 + j], acc[j]);
        }
        __syncthreads();
    }
    const int m = m0 + ty;
#pragma unroll
    for (int j = 0; j < 4; ++j) {
        const int n = n0 + tx * 4 + j;
        if (n < 720) Wc[(size_t)m * 720 + n] = acc[j];
    }
}

__global__ __launch_bounds__(256) void bc_k(
    const float* __restrict__ W2, const float* __restrict__ b1,
    const float* __restrict__ b2, float* __restrict__ bc)
{
    const int m = blockIdx.x * 256 + threadIdx.x;
    if (m >= 512) return;
    float a = b2[m];
    for (int h = 0; h < 512; ++h) a += W2[m * 512 + h] * b1[h];
    bc[m] = a;
}

// 32x32x16 A-frags, K permuted (kp = tap*80+ci), 720 = 45*16 exactly.
__global__ __launch_bounds__(256) void swz_wc2(
    const float* __restrict__ Wc, f16* __restrict__ Wcsw2)
{
    const int idx = blockIdx.x * 256 + threadIdx.x;
    if (idx >= 45 * 16 * 64) return;
    const int lane = idx & 63;
    const int t = idx >> 6;
    const int mtg = t & 15, ks = t >> 4;
    const int m = mtg * 32 + (lane & 31);
    const int k0 = ks * 16 + (lane >> 5) * 8;
    h8_t v;
#pragma unroll
    for (int j = 0; j < 8; ++j) {
        const int kp = k0 + j;
        const int tap = kp / 80, ci = kp - tap * 80;
        v[j] = (f16)Wc[(size_t)m * 720 + ci * 9 + tap];
    }
    *(h8_t*)(Wcsw2 + (size_t)idx * 8) = v;
}

// 32x32x16 A-frags for W3 (80x512 padded to 96 rows).
__global__ __launch_bounds__(256) void swz_w32(
    const float* __restrict__ W3, f16* __restrict__ W3sw2)
{
    const int idx = blockIdx.x * 256 + threadIdx.x;
    if (idx >= 32 * 3 * 64) return;
    const int lane = idx & 63;
    const int t = idx >> 6;
    const int mt = t % 3, ks2 = t / 3;
    const int m = mt * 32 + (lane & 31);
    const int k0 = ks2 * 16 + (lane >> 5) * 8;
    h8_t v;
#pragma unroll
    for (int j = 0; j < 8; ++j)
        v[j] = (f16)((m < 80) ? W3[(size_t)m * 512 + k0 + j] : 0.f);
    *(h8_t*)(W3sw2 + (size_t)idx * 8) = v;
}

// Seed: U_{-1} := S_0 (ch-major fp32), A_{-1} := S_0 ch0.
__global__ __launch_bounds__(256) void seed2(
    const float* __restrict__ z, float* __restrict__ U0,
    float* __restrict__ A0)
{
    const int idx = blockIdx.x * 256 + threadIdx.x;
    if (idx >= 640) return;
    const int b = idx / 80, c = idx - b * 80;
    const int n = b * 1024 + 16 * 32 + 16;
    const float v = (c == 0) ? 1.f : z[b * 100 + (c - 1)];
    U0[(size_t)c * NPIX + n] = v;
    if (c == 0) A0[n] = 1.f;
}

// ---------------------------------------------------------------------------
// kS: one full CA step, 2 rows per block. grid 128 x 1024 thr.
//   blk: b = blk>>4, yg = blk&15, rows y0 = 2*yg .. y0+1.
// ---------------------------------------------------------------------------
__global__ __launch_bounds__(1024) void kS(
    const f16* __restrict__ Wcsw2, const float* __restrict__ bc,
    const f16* __restrict__ W3sw2, const float* __restrict__ b3,
    const float* __restrict__ Uin, const float* __restrict__ Ain,
    float* __restrict__ Uout, float* __restrict__ Aout)
{
    __shared__ f16   msT[10880];    // 10 cc x (4 rows x 34 px) x 8 halfs
    __shared__ f16   Hsw[32768];    // 64 octets x 64 px x 8 halfs = 64 KB
    __shared__ float bcL[512];
    __shared__ float b3L[80];
    __shared__ float SrowL[2][2560];// S_s own rows, fp32
    __shared__ float N6[192];       // U ch0 rows y0-2..y0+3
    __shared__ float A6[192];       // alpha  rows y0-2..y0+3
    __shared__ float live4[128];    // live mask rows y0-1..y0+2

    const int tid = threadIdx.x;
    const int lane = tid & 63, w = tid >> 6;     // w = 0..15 (m-tile)
    const int li = lane & 31, q2 = lane >> 5;
    const int blk = blockIdx.x;
    const int b = blk >> 4, yg = blk & 15;
    const int y0 = yg * 2;
    const int gb = b * 1024;

    // early weight-ring prefetch (in flight during the build phase)
    h8_t aring[6];
#pragma unroll
    for (int pk = 0; pk < 6; ++pk)
        aring[pk] = *(const h8_t*)(Wcsw2 +
            (((size_t)pk * 16 + w) * 64 + lane) * 8);

    if (tid < 512) bcL[tid] = bc[tid];
    if (tid < 80)  b3L[tid] = b3[tid];

    // ---------------- build phase ----------------------------------------
    if (tid < 192) {
        const int r = tid >> 5, x = tid & 31, yy = y0 - 2 + r;
        const bool ok = ((unsigned)yy < 32u);
        N6[tid] = ok ? Uin[gb + yy * 32 + x] : -1e30f;
        A6[tid] = ok ? Ain[gb + yy * 32 + x] : -1e30f;
    }
    if (tid < 80) {  // zero halo columns xi = 0, 33 (all 4 msT rows)
        const int cc = tid >> 3, rem = tid & 7;
        const int r = rem >> 1, xi = (rem & 1) * 33;
        h8_t zz;
#pragma unroll
        for (int j = 0; j < 8; ++j) zz[j] = (f16)0.f;
        *(h8_t*)(msT + (size_t)(cc * 136 + r * 34 + xi) * 8) = zz;
    }
    __syncthreads();

    if (tid < 128) {  // live(r,x), rows y0-1..y0+2
        const int r = tid >> 5, x = tid & 31;
        float mN = -1e30f, mA = -1e30f;
#pragma unroll
        for (int rr = 0; rr < 3; ++rr)
#pragma unroll
            for (int dx = -1; dx <= 1; ++dx) {
                const int xx = x + dx;
                if ((unsigned)xx < 32u) {
                    mN = fmaxf(mN, N6[(r + rr) * 32 + xx]);
                    mA = fmaxf(mA, A6[(r + rr) * 32 + xx]);
                }
            }
        live4[tid] = (mN > T_ALIVE && mA > T_ALIVE) ? 1.f : 0.f;
    }
    __syncthreads();

    // S_s = Uin * live: 4 rows x 80 ch x 32 px = 10240 elems
#pragma unroll
    for (int it = 0; it < 10; ++it) {
        const int e = tid + it * 1024;
        const int x = e & 31;
        const int t2 = e >> 5;
        const int r = t2 / 80, ch = t2 - r * 80;
        const int yy = y0 - 1 + r;
        float v = 0.f;
        if ((unsigned)yy < 32u)
            v = Uin[(size_t)ch * NPIX + gb + yy * 32 + x] * live4[r * 32 + x];
        msT[(size_t)((ch >> 3) * 136 + r * 34 + x + 1) * 8 + (ch & 7)] = (f16)v;
        if (r == 1 || r == 2) {
            SrowL[r - 1][ch * 32 + x] = v;
            if (ch == 0) Aout[gb + (y0 + r - 1) * 32 + x] = v;
        }
    }
    __syncthreads();

    // ---------------- phase 1: 32 H-ch x 64 px per wave -------------------
    int pxh[9];
#pragma unroll
    for (int t = 0; t < 9; ++t)
        pxh[t] = ((t / 3) * 34 + li + (t % 3)) * 8;

    fx16 acc0, acc1;
#pragma unroll
    for (int r = 0; r < 16; ++r) { acc0[r] = 0.f; acc1[r] = 0.f; }

#pragma unroll
    for (int ks = 0; ks < 45; ++ks) {
        const int o0 = 2 * ks, o1 = 2 * ks + 1;
        const int a0 = (o0 % 10) * 1088 + pxh[o0 / 10];
        const int a1 = (o1 % 10) * 1088 + pxh[o1 / 10];
        const int ab = q2 ? a1 : a0;
        const h8_t bf0 = *(const h8_t*)(msT + ab);        // row y0
        const h8_t bf1 = *(const h8_t*)(msT + ab + 272);  // row y0+1
        const h8_t av = aring[ks % 6];
        if (ks + 6 < 45)
            aring[ks % 6] = *(const h8_t*)(Wcsw2 +
                (((size_t)(ks + 6) * 16 + w) * 64 + lane) * 8);
        acc0 = __builtin_amdgcn_mfma_f32_32x32x16_f16(av, bf0, acc0, 0, 0, 0);
        acc1 = __builtin_amdgcn_mfma_f32_32x32x16_f16(av, bf1, acc1, 0, 0, 0);
    }

    // relu(acc + bc) -> Hsw octets (co = ch/8, px = r*32+li)
#pragma unroll
    for (int aa = 0; aa < 4; ++aa) {
        const int chl = 8 * aa + 4 * q2;
        const int co = w * 4 + aa;
        h4_t v0, v1;
#pragma unroll
        for (int rb = 0; rb < 4; ++rb) {
            const float bb = bcL[w * 32 + chl + rb];
            v0[rb] = (f16)fmaxf(acc0[aa * 4 + rb] + bb, 0.f);
            v1[rb] = (f16)fmaxf(acc1[aa * 4 + rb] + bb, 0.f);
        }
        *(h4_t*)(Hsw + ((size_t)co * 64 +      li) * 8 + 4 * q2) = v0;
        *(h4_t*)(Hsw + ((size_t)co * 64 + 32 + li) * 8 + 4 * q2) = v1;
    }
    __syncthreads();

    // ---------------- phase 2: upd = W3*H full-K (waves 0..5) -------------
    if (w < 6) {
        const int mt = w >> 1, r = w & 1;
        h8_t ar[8];
#pragma unroll
        for (int pk = 0; pk < 8; ++pk)
            ar[pk] = *(const h8_t*)(W3sw2 +
                (((size_t)pk * 3 + mt) * 64 + lane) * 8);

        fx16 acc3;
#pragma unroll
        for (int rr = 0; rr < 16; ++rr) acc3[rr] = 0.f;
#pragma unroll
        for (int ks2 = 0; ks2 < 32; ++ks2) {
            const h8_t bf = *(const h8_t*)(Hsw +
                ((size_t)(ks2 * 2 + q2) * 64 + r * 32 + li) * 8);
            const h8_t a = ar[ks2 & 7];
            if (ks2 + 8 < 32)
                ar[ks2 & 7] = *(const h8_t*)(W3sw2 +
                    (((size_t)(ks2 + 8) * 3 + mt) * 64 + lane) * 8);
            acc3 = __builtin_amdgcn_mfma_f32_32x32x16_f16(a, bf, acc3, 0, 0, 0);
        }

        // U = S_s + upd + b3 (unmasked); next step's build applies the mask
        const size_t px = (size_t)(gb + (y0 + r) * 32 + li);
#pragma unroll
        for (int aa = 0; aa < 4; ++aa)
#pragma unroll
            for (int rb = 0; rb < 4; ++rb) {
                const int ch = mt * 32 + rb + 8 * aa + 4 * q2;
                if (ch < 80) {
                    Uout[(size_t)ch * NPIX + px] =
                        SrowL[r][ch * 32 + li] + acc3[aa * 4 + rb] + b3L[ch];
                }
            }
    }
}

// ---------------------------------------------------------------------------
// kF: dout = U63 ch0 * live63. grid 256 x 128 thr: b = blk>>5, y = blk&31.
// ---------------------------------------------------------------------------
__global__ __launch_bounds__(128) void kF(
    const float* __restrict__ Uf, const float* __restrict__ Af,
    float* __restrict__ dout)
{
    __shared__ float N3[96];
    __shared__ float A3[96];
    const int tid = threadIdx.x;
    const int blk = blockIdx.x;
    const int b = blk >> 5, y = blk & 31;
    const int gb = b * 1024;

    if (tid < 96) {
        const int r = tid >> 5, x = tid & 31, yy = y - 1 + r;
        const bool ok = ((unsigned)yy < 32u);
        N3[tid] = ok ? Uf[gb + yy * 32 + x] : -1e30f;
        A3[tid] = ok ? Af[gb + yy * 32 + x] : -1e30f;
    }
    __syncthreads();

    if (tid < 32) {
        float mN = -1e30f, mA = -1e30f;
#pragma unroll
        for (int rr = 0; rr < 3; ++rr)
#pragma unroll
            for (int dx = -1; dx <= 1; ++dx) {
                const int xx = tid + dx;
                if ((unsigned)xx < 32u) {
                    mN = fmaxf(mN, N3[rr * 32 + xx]);
                    mA = fmaxf(mA, A3[rr * 32 + xx]);
                }
            }
        const float lv = (mN > T_ALIVE && mA > T_ALIVE) ? 1.f : 0.f;
        dout[gb + y * 32 + tid] = Uf[gb + y * 32 + tid] * lv;
    }
}

// ---------------------------------------------------------------------------
extern "C" void kernel_launch(void* const* d_in, const int* in_sizes, int n_in,
                              void* d_out, int out_size, void* d_ws, size_t ws_size,
                              hipStream_t stream)
{
    const float* z  = (const float*)d_in[0];
    const float* W1 = (const float*)d_in[1];   // 512 x 720
    const float* b1 = (const float*)d_in[2];
    const float* W2 = (const float*)d_in[3];   // 512 x 512
    const float* b2 = (const float*)d_in[4];
    const float* W3 = (const float*)d_in[5];   // 80 x 512
    const float* b3 = (const float*)d_in[6];

    char* ws = (char*)d_ws;
    float* U0    = (float*)ws;  ws += (size_t)80 * NPIX * 4;
    float* U1    = (float*)ws;  ws += (size_t)80 * NPIX * 4;
    float* A0    = (float*)ws;  ws += (size_t)NPIX * 4;
    float* A1    = (float*)ws;  ws += (size_t)NPIX * 4;
    float* bc    = (float*)ws;  ws += 512 * 4;
    float* Wc    = (float*)ws;  ws += (size_t)512 * 720 * 4;
    float* W2T   = (float*)ws;  ws += (size_t)512 * 512 * 4;
    f16*   Wcsw2 = (f16*)ws;   ws += (size_t)45 * 16 * 64 * 8 * 2;
    f16*   W3sw2 = (f16*)ws;   ws += (size_t)32 * 3 * 64 * 8 * 2;

    hipMemsetAsync(U0, 0, (size_t)80 * NPIX * 4, stream);
    hipMemsetAsync(A0, 0, (size_t)NPIX * 4, stream);
    seed2<<<3, 256, 0, stream>>>(z, U0, A0);
    tr512<<<256, 256, 0, stream>>>(W2, W2T);
    wc32<<<dim3(23, 16), 256, 0, stream>>>(W2T, W1, Wc);
    bc_k<<<2, 256, 0, stream>>>(W2, b1, b2, bc);
    swz_wc2<<<180, 256, 0, stream>>>(Wc, Wcsw2);
    swz_w32<<<24, 256, 0, stream>>>(W3, W3sw2);

    float* Uc = U0;  float* Un = U1;
    float* Ac = A0;  float* An = A1;
    for (int s = 0; s < 64; ++s) {
        kS<<<128, 1024, 0, stream>>>(Wcsw2, bc, W3sw2, b3, Uc, Ac, Un, An);
        float* t = Uc; Uc = Un; Un = t;
        float* a = Ac; Ac = An; An = a;
    }
    kF<<<256, 128, 0, stream>>>(Uc, Ac, (float*)d_out);
}